// Round 4
// baseline (505.878 us; speedup 1.0000x reference)
//
#include <hip/hip_runtime.h>
#include <stdint.h>

// MinkFormerBlock on MI355X (gfx950). I/O: f32 in, f32 out (verified R8).
// R17: per-wave register A-gather, COMPILER-VISIBLE loads. R16 faulted: (a)
// asm-loaded idx registers could be copied/split by the allocator before the
// manual vmcnt retired them (garbage gather address -> page fault at ~240
// VGPR pressure), (b) waits after the barrier only certify the wave's OWN
// B-DMAs -> cross-wave LDS race. Now: idx and A are PLAIN loads (post-RA
// waitcnt pass protects every copy/spill with exact counted waits computed
// from the full op stream); B stays on global_load_lds. Manual asm waits
// remain only for what the compiler never does: certify own-B BEFORE the
// per-tap barrier (R15's proven discipline), counted so prefetch never
// drains. One barrier per tap. Steady-state ledger entering tap t =
// [A(t)8, idx(t+1)2]: stageB(t+1)->18 | vmcnt(8) retires A(t),idx(t+1)
// (~1800cyc cover) | loadA(t+1)+loadIdx(t+2)->18 | compute(t) |
// vmcnt(10)+lgkm(0) retires B(t+1) | barrier. Waits are set-based (robust
// to in-region load reorder); sched_barrier(0) pins region boundaries.
//
//   cvt:       xb = bf16(x)            (aliases h_b, dead until ew1)
//   wt:        WT* = bf16(W^T)  [tap][Cout][Cin]
//   gg<1,0>:   a = xb @ Wa1 ; v = xb @ Wv1     (bf16)
//   gg<125,1>: g = gather(a,nbr5)@W5 * v       (bf16, fused gate)
//   gg<27,2>:  t = gather(g,nbr3a)@W31         (f32)
//   bn+fin -> sc1,sh1 ; ew1: res=bf16->g_b, h=bf16(relu)->h_b
//   gg<27,2>:  t2 = gather(h,nbr3b)@W32        (f32)
//   bn+fin -> sc2,sh2 ; ew2: d_out = relu(t2*sc+sh + res)  (f32)

#define NPTS 32768
#define C 128
#define EPS 1e-5f

typedef unsigned short u16;
using bfrag = __attribute__((ext_vector_type(8))) short;   // 8 bf16 = 4 VGPRs
using f32x4 = __attribute__((ext_vector_type(4))) float;

__device__ __forceinline__ float b2f(u16 u) {
  union { unsigned int i; float f; } x;
  x.i = ((unsigned int)u) << 16;
  return x.f;
}
__device__ __forceinline__ u16 f2b(float f) {
  union { float f; unsigned int i; } x;
  x.f = f;
  unsigned int r = x.i + 0x7FFFu + ((x.i >> 16) & 1u);   // RNE
  return (u16)(r >> 16);
}

// async global->LDS, 16 B per lane; LDS dest is wave-uniform base + lane*16.
__device__ __forceinline__ void g2l16(const void* g, void* l) {
  __builtin_amdgcn_global_load_lds(
      (const __attribute__((address_space(1))) unsigned int*)g,
      (__attribute__((address_space(3))) unsigned int*)l,
      16, 0, 0);
}

// counted vmcnt wait + scheduling fence
#define GG_W(N)                                                            \
  asm volatile("s_waitcnt vmcnt(" #N ")" ::: "memory");                    \
  __builtin_amdgcn_sched_barrier(0)

// counted vmcnt + lgkm drain, then block barrier (own-B certified BEFORE
// the barrier -> union certified after; lgkm drains ds_reads for WAR)
#define GG_WB(N)                                                           \
  asm volatile("s_waitcnt vmcnt(" #N ") lgkmcnt(0)" ::: "memory");         \
  __builtin_amdgcn_s_barrier();                                            \
  __builtin_amdgcn_sched_barrier(0)

// =====================================================================
// Gather-GEMM. Block = 128x128 output, 4 waves row-split: wave wv owns rows
// [wv*32,+32) x all 128 cols; acc 2x8 mfma_f32_16x16x32_bf16 fragments.
// A: per-wave register gather, double-buffered (af0/af1 = 2x[2][4] bfrag),
//    plain global_load_dwordx4 (8/tap): lane (lsub,lm) reads 16B of row
//    id[rt] at byte kk*64+lsub*16.
// B: LDS 64KB = 2 x 32KB full-tap buffers [col][256B], staged via
//    global_load_lds (8 x 1KB instrs/wave), XOR chunk swizzle (slot s
//    holds global chunk s^(col&7)); ds_read_b128 at (kk*4+lsub)^(col&7)
//    measured conflict-free (R15: SQ_LDS_BANK_CONFLICT = 0).
// EPI: 0 bf16 out; 1 bf16(acc*vmul); 2 f32 out.
// =====================================================================
template <int NTAPS, int EPI>
__global__ __launch_bounds__(256, 1)
void gg_kernel(const u16* __restrict__ src, const u16* __restrict__ WT,
               const int* __restrict__ nbr, u16* __restrict__ outb,
               float* __restrict__ outf, const u16* __restrict__ vmul) {
  __shared__ uint4 lds[4096];          // 64 KB: two 32 KB B buffers
  char* const b0 = (char*)lds;
  char* const b1 = (char*)lds + 32768;

  const int tid  = threadIdx.x;
  const int lane = tid & 63;
  const int wv   = tid >> 6;
  const int lsub = lane >> 4, lm = lane & 15;
  const int row0 = blockIdx.x * 128;

  f32x4 acc[2][8];
#pragma unroll
  for (int i = 0; i < 2; i++)
#pragma unroll
    for (int j = 0; j < 8; j++) acc[i][j] = (f32x4)(0.0f);

  // ---- B stage: full tap (128 cols x 256 B) into buffer nb (8 DMA/wave)
  auto stageB = [&](char* nb, int t) {
    const char* wt = (const char*)WT + ((size_t)t << 15);
#pragma unroll
    for (int j = 0; j < 8; j++) {
      const int col = wv * 32 + j * 4 + lsub;
      g2l16(wt + ((size_t)col << 8) + ((lm ^ (col & 7)) << 4),
            nb + (wv * 32 + j * 4) * 256);
    }
  };

  // ---- idx loads (plain: waitcnt pass protects all copies/spills)
  auto loadIdx = [&](int (&d)[2], int t) {
#pragma unroll
    for (int rt = 0; rt < 2; rt++) {
      const int gr = row0 + wv * 32 + rt * 16 + lm;
      d[rt] = nbr[(size_t)gr * NTAPS + t];
    }
  };

  // ---- A gather: 8 plain dwordx4 into register fragments (per-wave)
  auto loadA = [&](bfrag (&af)[2][4], const int (&id)[2]) {
#pragma unroll
    for (int rt = 0; rt < 2; rt++) {
      const char* rb = (const char*)src + ((size_t)(unsigned)id[rt] << 8)
                     + lsub * 16;
#pragma unroll
      for (int kk = 0; kk < 4; kk++)
        af[rt][kk] = *(const bfrag*)(rb + kk * 64);
    }
  };

  // ---- one tap of MFMA: A from regs, B from LDS buffer buf
  auto computeT = [&](const bfrag (&af)[2][4], const char* buf) {
#pragma unroll
    for (int kk = 0; kk < 4; kk++) {
      bfrag bg[8];
#pragma unroll
      for (int ct = 0; ct < 8; ct++) {
        const int col = ct * 16 + lm;
        bg[ct] = *(const bfrag*)(buf + col * 256
                                 + (((kk * 4 + lsub) ^ (col & 7)) << 4));
      }
#pragma unroll
      for (int rt = 0; rt < 2; rt++)
#pragma unroll
        for (int ct = 0; ct < 8; ct++)
          acc[rt][ct] = __builtin_amdgcn_mfma_f32_16x16x32_bf16(
              af[rt][kk], bg[ct], acc[rt][ct], 0, 0, 0);
    }
  };

  bfrag af0[2][4], af1[2][4];

  if constexpr (NTAPS == 1) {
    // dense 1x1: identity rows, single B stage, full drain before compute
#pragma unroll
    for (int rt = 0; rt < 2; rt++)
#pragma unroll
      for (int kk = 0; kk < 4; kk++)
        af0[rt][kk] = *(const bfrag*)((const char*)src
            + (size_t)(row0 + wv * 32 + rt * 16 + lm) * 256
            + kk * 64 + lsub * 16);
    stageB(b0, 0);
    GG_WB(0);
    computeT(af0, b0);
  } else {
    int idE[2], idO[2];              // even-tap / odd-tap index sets
    // ---- prologue: idx(0),idx(1) -> A(0),B(0) -> full drain + barrier
    loadIdx(idE, 0);                 // 2 ops
    loadIdx(idO, 1);                 // 2
    GG_W(2);                         // idx(0) ready
    loadA(af0, idE);                 // 8  A(0)
    stageB(b0, 0);                   // 8  B(0)
    GG_WB(0);                        // everything landed; entering tap 0: []

#pragma unroll 1
    for (int t = 0; t < NTAPS - 3; t += 2) {
      // ---- even tap t: compute af0 from b0
      stageB(b1, t + 1);             // -> [A(t)8, idx(t+1)2, B(t+1)8]
      GG_W(8);                       // retire A(t)+idx(t+1)  (t=0: no-op)
      loadA(af1, idO);               // A(t+1)
      loadIdx(idE, t + 2);
      __builtin_amdgcn_sched_barrier(0);
      computeT(af0, b0);
      GG_WB(10);                     // retire B(t+1); leave [A(t+1)8, idx2]
      // ---- odd tap t+1: compute af1 from b1
      stageB(b0, t + 2);
      GG_W(8);                       // retire A(t+1)+idx(t+2)
      loadA(af0, idE);               // A(t+2)
      loadIdx(idO, t + 3);
      __builtin_amdgcn_sched_barrier(0);
      computeT(af1, b1);
      GG_WB(10);                     // retire B(t+2)
    }
    // ---- tap NTAPS-3 (even)
    stageB(b1, NTAPS - 2);
    GG_W(8);
    loadA(af1, idO);                 // A(N-2)
    loadIdx(idE, NTAPS - 1);
    __builtin_amdgcn_sched_barrier(0);
    computeT(af0, b0);
    GG_WB(10);
    // ---- tap NTAPS-2 (odd): last B stage, last A load
    stageB(b0, NTAPS - 1);
    GG_W(8);                         // retire A(N-2)+idx(N-1)
    loadA(af0, idE);                 // A(N-1)
    __builtin_amdgcn_sched_barrier(0);
    computeT(af1, b1);
    GG_WB(8);                        // retire B(N-1); leave [A(N-1)8]
    // ---- tap NTAPS-1 (even)
    GG_W(0);                         // retire A(N-1)
    computeT(af0, b0);
  }

  // ---- epilogue write. C/D: col = lane&15, row = lsub*4 + reg.
#pragma unroll
  for (int rt = 0; rt < 2; rt++) {
    const int rowb = row0 + wv * 32 + rt * 16 + lsub * 4;
#pragma unroll
    for (int ct = 0; ct < 8; ct++) {
      const int c = ct * 16 + lm;
#pragma unroll
      for (int reg = 0; reg < 4; reg++) {
        const size_t off = (size_t)(rowb + reg) * C + c;
        const float v = acc[rt][ct][reg];
        if (EPI == 0)      outb[off] = f2b(v);
        else if (EPI == 1) outb[off] = f2b(v * b2f(vmul[off]));
        else               outf[off] = v;
      }
    }
  }
}

// ---- f32 -> bf16 bulk convert (for x) ------------------------------------
__global__ __launch_bounds__(256)
void cvt_kernel(const float* __restrict__ x, u16* __restrict__ xb) {
  const int i = (blockIdx.x * 256 + threadIdx.x) * 4;
  const float4 v = *(const float4*)(x + i);
  ushort4 o;
  o.x = f2b(v.x); o.y = f2b(v.y); o.z = f2b(v.z); o.w = f2b(v.w);
  *(ushort4*)(xb + i) = o;
}

// ---- weights: f32 [..,Cin,Cout] -> bf16 [..,Cout,Cin] --------------------
__global__ __launch_bounds__(256)
void wt_kernel(const float* __restrict__ W5, const float* __restrict__ W31,
               const float* __restrict__ W32, const float* __restrict__ Wa1,
               const float* __restrict__ Wv1,
               u16* __restrict__ T5, u16* __restrict__ T31, u16* __restrict__ T32,
               u16* __restrict__ Ta1, u16* __restrict__ Tv1) {
  const int b = blockIdx.x;
  const float* w;
  u16* o;
  if (b < 125)       { w = W5  + (size_t)b * 16384;         o = T5  + (size_t)b * 16384; }
  else if (b < 152)  { w = W31 + (size_t)(b - 125) * 16384; o = T31 + (size_t)(b - 125) * 16384; }
  else if (b < 179)  { w = W32 + (size_t)(b - 152) * 16384; o = T32 + (size_t)(b - 152) * 16384; }
  else if (b == 179) { w = Wa1; o = Ta1; }
  else               { w = Wv1; o = Tv1; }
  __shared__ u16 tile[128 * 129];
  for (int i = threadIdx.x; i < C * C; i += 256)
    tile[(i & 127) * 129 + (i >> 7)] = f2b(w[i]);
  __syncthreads();
  for (int i = threadIdx.x; i < C * C; i += 256)
    o[i] = tile[(i >> 7) * 129 + (i & 127)];
}

// ---- BN partials (f32): block b owns rows [b*128, +128) ------------------
__global__ __launch_bounds__(256)
void bnp_kernel(const float* __restrict__ t, float* __restrict__ psum,
                float* __restrict__ psq) {
  const int b = blockIdx.x;
  const int c = threadIdx.x & 127;
  const int h = threadIdx.x >> 7;
  const float* p = t + (size_t)(b * 128 + h * 64) * C + c;
  float s = 0.f, q = 0.f;
#pragma unroll 8
  for (int j = 0; j < 64; j++) {
    const float v = p[(size_t)j * C];
    s += v; q += v * v;
  }
  __shared__ float ls[256], lq[256];
  ls[threadIdx.x] = s; lq[threadIdx.x] = q;
  __syncthreads();
  if (h == 0) {
    psum[b * 128 + c] = ls[c] + ls[c + 128];
    psq[b * 128 + c]  = lq[c] + lq[c + 128];
  }
}

// ---- bnfin: block c reduces 256 partials (parallel) ----------------------
__global__ __launch_bounds__(256)
void bnfin_kernel(const float* __restrict__ psum, const float* __restrict__ psq,
                  const float* __restrict__ gamma, const float* __restrict__ beta,
                  float* __restrict__ scale, float* __restrict__ shift) {
  const int c = blockIdx.x;
  const int t = threadIdx.x;
  float s = psum[(size_t)t * 128 + c];
  float q = psq[(size_t)t * 128 + c];
#pragma unroll
  for (int o = 32; o > 0; o >>= 1) {
    s += __shfl_down(s, o);
    q += __shfl_down(q, o);
  }
  __shared__ float ls[4], lq[4];
  if ((t & 63) == 0) { ls[t >> 6] = s; lq[t >> 6] = q; }
  __syncthreads();
  if (t == 0) {
    s = ls[0] + ls[1] + ls[2] + ls[3];
    q = lq[0] + lq[1] + lq[2] + lq[3];
    const float mean = s * (1.0f / NPTS);
    const float var  = q * (1.0f / NPTS) - mean * mean;
    const float sc   = rsqrtf(var + EPS) * gamma[c];
    scale[c] = sc;
    shift[c] = beta[c] - mean * sc;
  }
}

// ---- ew1: o = t*sc+sh + x; res=bf16(o); h=bf16(relu o) -------------------
__global__ __launch_bounds__(256)
void ew1_kernel(const float* __restrict__ t, const float* __restrict__ x,
                const float* __restrict__ scale, const float* __restrict__ shift,
                u16* __restrict__ res, u16* __restrict__ h) {
  const int i = blockIdx.x * 256 + threadIdx.x;
  const int c = i & 127;
  const float o = t[i] * scale[c] + shift[c] + x[i];
  res[i] = f2b(o);
  h[i] = f2b(o < 0.f ? 0.f : o);
}

// ---- ew2: y = relu(t2*sc+sh + res) -> f32 d_out --------------------------
__global__ __launch_bounds__(256)
void ew2_kernel(const float* __restrict__ t2, const u16* __restrict__ res,
                const float* __restrict__ scale, const float* __restrict__ shift,
                float* __restrict__ y) {
  const int i = blockIdx.x * 256 + threadIdx.x;
  const int c = i & 127;
  const float o = t2[i] * scale[c] + shift[c] + b2f(res[i]);
  y[i] = o < 0.f ? 0.f : o;
}

// =====================================================================
extern "C" void kernel_launch(void* const* d_in, const int* in_sizes, int n_in,
                              void* d_out, int out_size, void* d_ws, size_t ws_size,
                              hipStream_t stream) {
  (void)in_sizes; (void)n_in; (void)out_size; (void)ws_size;

  const float* x   = (const float*)d_in[0];
  const float* Wa1 = (const float*)d_in[1];
  const float* Wv1 = (const float*)d_in[2];
  const float* W5  = (const float*)d_in[3];
  const float* W31 = (const float*)d_in[4];
  const float* W32 = (const float*)d_in[5];
  const float* g1  = (const float*)d_in[6];
  const float* b1  = (const float*)d_in[7];
  const float* g2  = (const float*)d_in[8];
  const float* b2  = (const float*)d_in[9];
  const int* nbr5  = (const int*)d_in[10];
  const int* nbr3a = (const int*)d_in[11];
  const int* nbr3b = (const int*)d_in[12];

  // ---- workspace (~39.8 MB) ----
  char* w = (char*)d_ws;
  u16* WT5  = (u16*)w; w += 4096000;
  u16* WT31 = (u16*)w; w += 884736;
  u16* WT32 = (u16*)w; w += 884736;
  u16* WTa1 = (u16*)w; w += 32768;
  u16* WTv1 = (u16*)w; w += 32768;
  char* AV  = w;       w += 16777216;          // a | v ; later t/t2 (f32)
  u16*   a_b = (u16*)AV;
  u16*   v_b = (u16*)(AV + 8388608);
  float* tf  = (float*)AV;
  u16* g_b  = (u16*)w; w += 8388608;           // g ; later res (bf16)
  u16* h_b  = (u16*)w; w += 8388608;           // xb first, then h (bf16)
  u16* xb   = h_b;                             // alias: xb dead before ew1
  float* psum = (float*)w; w += 131072;
  float* psq  = (float*)w; w += 131072;
  float* sc1  = (float*)w; w += 512;
  float* sh1  = (float*)w; w += 512;
  float* sc2  = (float*)w; w += 512;
  float* sh2  = (float*)w; w += 512;

  const dim3 B256(256), GG(NPTS / 128), GBN(256), GEW(NPTS * C / 256);
  float* yout = (float*)d_out;

  cvt_kernel<<<dim3(NPTS * C / 1024), B256, 0, stream>>>(x, xb);
  wt_kernel<<<dim3(181), B256, 0, stream>>>(W5, W31, W32, Wa1, Wv1,
                                            WT5, WT31, WT32, WTa1, WTv1);

  // a = xb @ Wa1 ; v = xb @ Wv1
  gg_kernel<1, 0><<<GG, B256, 0, stream>>>(xb, WTa1, nullptr, a_b, nullptr, nullptr);
  gg_kernel<1, 0><<<GG, B256, 0, stream>>>(xb, WTv1, nullptr, v_b, nullptr, nullptr);

  // g = gather125(a)@W5 * v
  gg_kernel<125, 1><<<GG, B256, 0, stream>>>(a_b, WT5, nbr5, g_b, nullptr, v_b);

  // t = gather27(g)@W31 -> f32 over AV (a,v dead)
  gg_kernel<27, 2><<<GG, B256, 0, stream>>>(g_b, WT31, nbr3a, nullptr, tf, nullptr);
  bnp_kernel<<<GBN, B256, 0, stream>>>(tf, psum, psq);
  bnfin_kernel<<<dim3(128), B256, 0, stream>>>(psum, psq, g1, b1, sc1, sh1);
  ew1_kernel<<<GEW, B256, 0, stream>>>(tf, x, sc1, sh1, g_b, h_b);   // res->g_b, h->h_b (xb dead)

  // t2 = gather27(h)@W32 -> f32 over AV (t dead)
  gg_kernel<27, 2><<<GG, B256, 0, stream>>>(h_b, WT32, nbr3b, nullptr, tf, nullptr);
  bnp_kernel<<<GBN, B256, 0, stream>>>(tf, psum, psq);
  bnfin_kernel<<<dim3(128), B256, 0, stream>>>(psum, psq, g2, b2, sc2, sh2);
  ew2_kernel<<<GEW, B256, 0, stream>>>(tf, g_b, sc2, sh2, yout);
}

// Round 5
// 501.681 us; speedup vs baseline: 1.0084x; 1.0084x over previous
//
#include <hip/hip_runtime.h>
#include <stdint.h>

// MinkFormerBlock on MI355X (gfx950). I/O: f32 in, f32 out (verified R8).
// R18: R17's structure + 128B-stride LDS B-tile. R17 regressed (263us,
// SQ_LDS_BANK_CONFLICT 1.64e7 == R13's value) because the 256B-stride
// [col][256B] tile re-introduced the bank conflict R15's 128B-stride layout
// measured at ZERO: the XOR swizzle only perturbs addr bits 4-7, and at
// 256B stride the ds_read_b128 pattern serializes ~4x (+1100 cyc/tap,
// exactly the 1832->2104 cyc/tap regression; VALUBusy 19->8 confirms the
// A-decoupling itself worked). Now B buffer = [half][128 col][128 B] (two
// half-K sub-tiles per 32KB buffer) staged by 8 x 1KB DMA/wave (ledger
// unchanged); k-step kk reads half kk>>1 at chunk ((kk&1)*4+lsub)^(col&7)
// -- bit-identical to R15's measured-conflict-free pattern.
// Structure (R17): A gathered per-wave into registers (plain loads, compiler
// waitcnt pass protects spills/copies), B via global_load_lds, one barrier
// per tap, own-B certified BEFORE barrier, counted vmcnt never drains.
// Steady ledger entering tap t = [A(t)8, idx(t+1)2]: stageB(t+1)->18 |
// vmcnt(8) | loadA(t+1)+loadIdx(t+2)->18 | compute(t) | vmcnt(10)+lgkm(0)
// | barrier. Tail: (8),(8 then 0).
//
//   cvt:       xb = bf16(x)            (aliases h_b, dead until ew1)
//   wt:        WT* = bf16(W^T)  [tap][Cout][Cin]
//   gg<1,0>:   a = xb @ Wa1 ; v = xb @ Wv1     (bf16)
//   gg<125,1>: g = gather(a,nbr5)@W5 * v       (bf16, fused gate)
//   gg<27,2>:  t = gather(g,nbr3a)@W31         (f32)
//   bn+fin -> sc1,sh1 ; ew1: res=bf16->g_b, h=bf16(relu)->h_b
//   gg<27,2>:  t2 = gather(h,nbr3b)@W32        (f32)
//   bn+fin -> sc2,sh2 ; ew2: d_out = relu(t2*sc+sh + res)  (f32)

#define NPTS 32768
#define C 128
#define EPS 1e-5f

typedef unsigned short u16;
using bfrag = __attribute__((ext_vector_type(8))) short;   // 8 bf16 = 4 VGPRs
using f32x4 = __attribute__((ext_vector_type(4))) float;

__device__ __forceinline__ float b2f(u16 u) {
  union { unsigned int i; float f; } x;
  x.i = ((unsigned int)u) << 16;
  return x.f;
}
__device__ __forceinline__ u16 f2b(float f) {
  union { float f; unsigned int i; } x;
  x.f = f;
  unsigned int r = x.i + 0x7FFFu + ((x.i >> 16) & 1u);   // RNE
  return (u16)(r >> 16);
}

// async global->LDS, 16 B per lane; LDS dest is wave-uniform base + lane*16.
__device__ __forceinline__ void g2l16(const void* g, void* l) {
  __builtin_amdgcn_global_load_lds(
      (const __attribute__((address_space(1))) unsigned int*)g,
      (__attribute__((address_space(3))) unsigned int*)l,
      16, 0, 0);
}

// counted vmcnt wait + scheduling fence
#define GG_W(N)                                                            \
  asm volatile("s_waitcnt vmcnt(" #N ")" ::: "memory");                    \
  __builtin_amdgcn_sched_barrier(0)

// counted vmcnt + lgkm drain, then block barrier (own-B certified BEFORE
// the barrier -> union certified after; lgkm drains ds_reads for WAR)
#define GG_WB(N)                                                           \
  asm volatile("s_waitcnt vmcnt(" #N ") lgkmcnt(0)" ::: "memory");         \
  __builtin_amdgcn_s_barrier();                                            \
  __builtin_amdgcn_sched_barrier(0)

// =====================================================================
// Gather-GEMM. Block = 128x128 output, 4 waves row-split: wave wv owns rows
// [wv*32,+32) x all 128 cols; acc 2x8 mfma_f32_16x16x32_bf16 fragments.
// A: per-wave register gather, double-buffered (af0/af1 = 2x[2][4] bfrag),
//    plain global_load_dwordx4 (8/tap): lane (lsub,lm) reads 16B of row
//    id[rt] at byte kk*64+lsub*16.
// B: LDS 64KB = 2 x 32KB buffers, each [half][128 col][128 B] (half = K/2).
//    Stage: 8 x 1KB DMA/wave; instr (j,h): cols wv*32+j*8..+7, half h;
//    lane (r8,cs8): global WT+col*256+h*128+((cs8^(col&7))<<4) -> LDS slot
//    cs8 of col's half-row (slot s holds global chunk s^(col&7)).
//    Read (kk,lsub): half kk>>1, chunk ((kk&1)*4+lsub)^(col&7) -- R15's
//    measured-zero-conflict pattern (128B stride).
// EPI: 0 bf16 out; 1 bf16(acc*vmul); 2 f32 out.
// =====================================================================
template <int NTAPS, int EPI>
__global__ __launch_bounds__(256, 1)
void gg_kernel(const u16* __restrict__ src, const u16* __restrict__ WT,
               const int* __restrict__ nbr, u16* __restrict__ outb,
               float* __restrict__ outf, const u16* __restrict__ vmul) {
  __shared__ uint4 lds[4096];          // 64 KB: two 32 KB B buffers
  char* const b0 = (char*)lds;
  char* const b1 = (char*)lds + 32768;

  const int tid  = threadIdx.x;
  const int lane = tid & 63;
  const int wv   = tid >> 6;
  const int lsub = lane >> 4, lm = lane & 15;
  const int r8   = lane >> 3;          // DMA: col within instr (0..7)
  const int cs8  = lane & 7;           // DMA: chunk slot (0..7, 16 B)
  const int row0 = blockIdx.x * 128;

  f32x4 acc[2][8];
#pragma unroll
  for (int i = 0; i < 2; i++)
#pragma unroll
    for (int j = 0; j < 8; j++) acc[i][j] = (f32x4)(0.0f);

  // ---- B stage: full tap into buffer nb, 8 DMA instrs/wave (4 col-groups
  // x 2 halves). 128B-stride layout: half h at nb + h*16384, col*128.
  auto stageB = [&](char* nb, int t) {
    const char* wt = (const char*)WT + ((size_t)t << 15);
#pragma unroll
    for (int j = 0; j < 4; j++) {
      const int col0 = wv * 32 + j * 8;
      const int col  = col0 + r8;
      const char* gp = wt + ((size_t)col << 8) + ((cs8 ^ (col & 7)) << 4);
      g2l16(gp,       nb + col0 * 128);            // half 0
      g2l16(gp + 128, nb + 16384 + col0 * 128);    // half 1
    }
  };

  // ---- idx loads (plain: waitcnt pass protects all copies/spills)
  auto loadIdx = [&](int (&d)[2], int t) {
#pragma unroll
    for (int rt = 0; rt < 2; rt++) {
      const int gr = row0 + wv * 32 + rt * 16 + lm;
      d[rt] = nbr[(size_t)gr * NTAPS + t];
    }
  };

  // ---- A gather: 8 plain dwordx4 into register fragments (per-wave)
  auto loadA = [&](bfrag (&af)[2][4], const int (&id)[2]) {
#pragma unroll
    for (int rt = 0; rt < 2; rt++) {
      const char* rb = (const char*)src + ((size_t)(unsigned)id[rt] << 8)
                     + lsub * 16;
#pragma unroll
      for (int kk = 0; kk < 4; kk++)
        af[rt][kk] = *(const bfrag*)(rb + kk * 64);
    }
  };

  // ---- one tap of MFMA: A from regs, B from LDS buffer buf
  auto computeT = [&](const bfrag (&af)[2][4], const char* buf) {
#pragma unroll
    for (int kk = 0; kk < 4; kk++) {
      const char* hb = buf + (kk >> 1) * 16384;
      bfrag bg[8];
#pragma unroll
      for (int ct = 0; ct < 8; ct++) {
        const int col = ct * 16 + lm;
        bg[ct] = *(const bfrag*)(hb + col * 128
                                 + ((((kk & 1) * 4 + lsub) ^ (col & 7)) << 4));
      }
#pragma unroll
      for (int rt = 0; rt < 2; rt++)
#pragma unroll
        for (int ct = 0; ct < 8; ct++)
          acc[rt][ct] = __builtin_amdgcn_mfma_f32_16x16x32_bf16(
              af[rt][kk], bg[ct], acc[rt][ct], 0, 0, 0);
    }
  };

  bfrag af0[2][4], af1[2][4];

  if constexpr (NTAPS == 1) {
    // dense 1x1: identity rows, single B stage, full drain before compute
#pragma unroll
    for (int rt = 0; rt < 2; rt++)
#pragma unroll
      for (int kk = 0; kk < 4; kk++)
        af0[rt][kk] = *(const bfrag*)((const char*)src
            + (size_t)(row0 + wv * 32 + rt * 16 + lm) * 256
            + kk * 64 + lsub * 16);
    stageB(b0, 0);
    GG_WB(0);
    computeT(af0, b0);
  } else {
    int idE[2], idO[2];              // even-tap / odd-tap index sets
    // ---- prologue: idx(0),idx(1) -> A(0),B(0) -> full drain + barrier
    loadIdx(idE, 0);                 // 2 ops
    loadIdx(idO, 1);                 // 2
    GG_W(2);                         // idx(0) ready
    loadA(af0, idE);                 // 8  A(0)
    stageB(b0, 0);                   // 8  B(0)
    GG_WB(0);                        // everything landed; entering tap 0: []

#pragma unroll 1
    for (int t = 0; t < NTAPS - 3; t += 2) {
      // ---- even tap t: compute af0 from b0
      stageB(b1, t + 1);             // -> [A(t)8, idx(t+1)2, B(t+1)8]
      GG_W(8);                       // retire A(t)+idx(t+1)  (t=0: no-op)
      loadA(af1, idO);               // A(t+1)
      loadIdx(idE, t + 2);
      __builtin_amdgcn_sched_barrier(0);
      computeT(af0, b0);
      GG_WB(10);                     // retire B(t+1); leave [A(t+1)8, idx2]
      // ---- odd tap t+1: compute af1 from b1
      stageB(b0, t + 2);
      GG_W(8);                       // retire A(t+1)+idx(t+2)
      loadA(af0, idE);               // A(t+2)
      loadIdx(idO, t + 3);
      __builtin_amdgcn_sched_barrier(0);
      computeT(af1, b1);
      GG_WB(10);                     // retire B(t+2)
    }
    // ---- tap NTAPS-3 (even)
    stageB(b1, NTAPS - 2);
    GG_W(8);
    loadA(af1, idO);                 // A(N-2)
    loadIdx(idE, NTAPS - 1);
    __builtin_amdgcn_sched_barrier(0);
    computeT(af0, b0);
    GG_WB(10);
    // ---- tap NTAPS-2 (odd): last B stage, last A load
    stageB(b0, NTAPS - 1);
    GG_W(8);                         // retire A(N-2)+idx(N-1)
    loadA(af0, idE);                 // A(N-1)
    __builtin_amdgcn_sched_barrier(0);
    computeT(af1, b1);
    GG_WB(8);                        // retire B(N-1); leave [A(N-1)8]
    // ---- tap NTAPS-1 (even)
    GG_W(0);                         // retire A(N-1)
    computeT(af0, b0);
  }

  // ---- epilogue write. C/D: col = lane&15, row = lsub*4 + reg.
#pragma unroll
  for (int rt = 0; rt < 2; rt++) {
    const int rowb = row0 + wv * 32 + rt * 16 + lsub * 4;
#pragma unroll
    for (int ct = 0; ct < 8; ct++) {
      const int c = ct * 16 + lm;
#pragma unroll
      for (int reg = 0; reg < 4; reg++) {
        const size_t off = (size_t)(rowb + reg) * C + c;
        const float v = acc[rt][ct][reg];
        if (EPI == 0)      outb[off] = f2b(v);
        else if (EPI == 1) outb[off] = f2b(v * b2f(vmul[off]));
        else               outf[off] = v;
      }
    }
  }
}

// ---- f32 -> bf16 bulk convert (for x) ------------------------------------
__global__ __launch_bounds__(256)
void cvt_kernel(const float* __restrict__ x, u16* __restrict__ xb) {
  const int i = (blockIdx.x * 256 + threadIdx.x) * 4;
  const float4 v = *(const float4*)(x + i);
  ushort4 o;
  o.x = f2b(v.x); o.y = f2b(v.y); o.z = f2b(v.z); o.w = f2b(v.w);
  *(ushort4*)(xb + i) = o;
}

// ---- weights: f32 [..,Cin,Cout] -> bf16 [..,Cout,Cin] --------------------
__global__ __launch_bounds__(256)
void wt_kernel(const float* __restrict__ W5, const float* __restrict__ W31,
               const float* __restrict__ W32, const float* __restrict__ Wa1,
               const float* __restrict__ Wv1,
               u16* __restrict__ T5, u16* __restrict__ T31, u16* __restrict__ T32,
               u16* __restrict__ Ta1, u16* __restrict__ Tv1) {
  const int b = blockIdx.x;
  const float* w;
  u16* o;
  if (b < 125)       { w = W5  + (size_t)b * 16384;         o = T5  + (size_t)b * 16384; }
  else if (b < 152)  { w = W31 + (size_t)(b - 125) * 16384; o = T31 + (size_t)(b - 125) * 16384; }
  else if (b < 179)  { w = W32 + (size_t)(b - 152) * 16384; o = T32 + (size_t)(b - 152) * 16384; }
  else if (b == 179) { w = Wa1; o = Ta1; }
  else               { w = Wv1; o = Tv1; }
  __shared__ u16 tile[128 * 129];
  for (int i = threadIdx.x; i < C * C; i += 256)
    tile[(i & 127) * 129 + (i >> 7)] = f2b(w[i]);
  __syncthreads();
  for (int i = threadIdx.x; i < C * C; i += 256)
    o[i] = tile[(i >> 7) * 129 + (i & 127)];
}

// ---- BN partials (f32): block b owns rows [b*128, +128) ------------------
__global__ __launch_bounds__(256)
void bnp_kernel(const float* __restrict__ t, float* __restrict__ psum,
                float* __restrict__ psq) {
  const int b = blockIdx.x;
  const int c = threadIdx.x & 127;
  const int h = threadIdx.x >> 7;
  const float* p = t + (size_t)(b * 128 + h * 64) * C + c;
  float s = 0.f, q = 0.f;
#pragma unroll 8
  for (int j = 0; j < 64; j++) {
    const float v = p[(size_t)j * C];
    s += v; q += v * v;
  }
  __shared__ float ls[256], lq[256];
  ls[threadIdx.x] = s; lq[threadIdx.x] = q;
  __syncthreads();
  if (h == 0) {
    psum[b * 128 + c] = ls[c] + ls[c + 128];
    psq[b * 128 + c]  = lq[c] + lq[c + 128];
  }
}

// ---- bnfin: block c reduces 256 partials (parallel) ----------------------
__global__ __launch_bounds__(256)
void bnfin_kernel(const float* __restrict__ psum, const float* __restrict__ psq,
                  const float* __restrict__ gamma, const float* __restrict__ beta,
                  float* __restrict__ scale, float* __restrict__ shift) {
  const int c = blockIdx.x;
  const int t = threadIdx.x;
  float s = psum[(size_t)t * 128 + c];
  float q = psq[(size_t)t * 128 + c];
#pragma unroll
  for (int o = 32; o > 0; o >>= 1) {
    s += __shfl_down(s, o);
    q += __shfl_down(q, o);
  }
  __shared__ float ls[4], lq[4];
  if ((t & 63) == 0) { ls[t >> 6] = s; lq[t >> 6] = q; }
  __syncthreads();
  if (t == 0) {
    s = ls[0] + ls[1] + ls[2] + ls[3];
    q = lq[0] + lq[1] + lq[2] + lq[3];
    const float mean = s * (1.0f / NPTS);
    const float var  = q * (1.0f / NPTS) - mean * mean;
    const float sc   = rsqrtf(var + EPS) * gamma[c];
    scale[c] = sc;
    shift[c] = beta[c] - mean * sc;
  }
}

// ---- ew1: o = t*sc+sh + x; res=bf16(o); h=bf16(relu o) -------------------
__global__ __launch_bounds__(256)
void ew1_kernel(const float* __restrict__ t, const float* __restrict__ x,
                const float* __restrict__ scale, const float* __restrict__ shift,
                u16* __restrict__ res, u16* __restrict__ h) {
  const int i = blockIdx.x * 256 + threadIdx.x;
  const int c = i & 127;
  const float o = t[i] * scale[c] + shift[c] + x[i];
  res[i] = f2b(o);
  h[i] = f2b(o < 0.f ? 0.f : o);
}

// ---- ew2: y = relu(t2*sc+sh + res) -> f32 d_out --------------------------
__global__ __launch_bounds__(256)
void ew2_kernel(const float* __restrict__ t2, const u16* __restrict__ res,
                const float* __restrict__ scale, const float* __restrict__ shift,
                float* __restrict__ y) {
  const int i = blockIdx.x * 256 + threadIdx.x;
  const int c = i & 127;
  const float o = t2[i] * scale[c] + shift[c] + b2f(res[i]);
  y[i] = o < 0.f ? 0.f : o;
}

// =====================================================================
extern "C" void kernel_launch(void* const* d_in, const int* in_sizes, int n_in,
                              void* d_out, int out_size, void* d_ws, size_t ws_size,
                              hipStream_t stream) {
  (void)in_sizes; (void)n_in; (void)out_size; (void)ws_size;

  const float* x   = (const float*)d_in[0];
  const float* Wa1 = (const float*)d_in[1];
  const float* Wv1 = (const float*)d_in[2];
  const float* W5  = (const float*)d_in[3];
  const float* W31 = (const float*)d_in[4];
  const float* W32 = (const float*)d_in[5];
  const float* g1  = (const float*)d_in[6];
  const float* b1  = (const float*)d_in[7];
  const float* g2  = (const float*)d_in[8];
  const float* b2  = (const float*)d_in[9];
  const int* nbr5  = (const int*)d_in[10];
  const int* nbr3a = (const int*)d_in[11];
  const int* nbr3b = (const int*)d_in[12];

  // ---- workspace (~39.8 MB) ----
  char* w = (char*)d_ws;
  u16* WT5  = (u16*)w; w += 4096000;
  u16* WT31 = (u16*)w; w += 884736;
  u16* WT32 = (u16*)w; w += 884736;
  u16* WTa1 = (u16*)w; w += 32768;
  u16* WTv1 = (u16*)w; w += 32768;
  char* AV  = w;       w += 16777216;          // a | v ; later t/t2 (f32)
  u16*   a_b = (u16*)AV;
  u16*   v_b = (u16*)(AV + 8388608);
  float* tf  = (float*)AV;
  u16* g_b  = (u16*)w; w += 8388608;           // g ; later res (bf16)
  u16* h_b  = (u16*)w; w += 8388608;           // xb first, then h (bf16)
  u16* xb   = h_b;                             // alias: xb dead before ew1
  float* psum = (float*)w; w += 131072;
  float* psq  = (float*)w; w += 131072;
  float* sc1  = (float*)w; w += 512;
  float* sh1  = (float*)w; w += 512;
  float* sc2  = (float*)w; w += 512;
  float* sh2  = (float*)w; w += 512;

  const dim3 B256(256), GG(NPTS / 128), GBN(256), GEW(NPTS * C / 256);
  float* yout = (float*)d_out;

  cvt_kernel<<<dim3(NPTS * C / 1024), B256, 0, stream>>>(x, xb);
  wt_kernel<<<dim3(181), B256, 0, stream>>>(W5, W31, W32, Wa1, Wv1,
                                            WT5, WT31, WT32, WTa1, WTv1);

  // a = xb @ Wa1 ; v = xb @ Wv1
  gg_kernel<1, 0><<<GG, B256, 0, stream>>>(xb, WTa1, nullptr, a_b, nullptr, nullptr);
  gg_kernel<1, 0><<<GG, B256, 0, stream>>>(xb, WTv1, nullptr, v_b, nullptr, nullptr);

  // g = gather125(a)@W5 * v
  gg_kernel<125, 1><<<GG, B256, 0, stream>>>(a_b, WT5, nbr5, g_b, nullptr, v_b);

  // t = gather27(g)@W31 -> f32 over AV (a,v dead)
  gg_kernel<27, 2><<<GG, B256, 0, stream>>>(g_b, WT31, nbr3a, nullptr, tf, nullptr);
  bnp_kernel<<<GBN, B256, 0, stream>>>(tf, psum, psq);
  bnfin_kernel<<<dim3(128), B256, 0, stream>>>(psum, psq, g1, b1, sc1, sh1);
  ew1_kernel<<<GEW, B256, 0, stream>>>(tf, x, sc1, sh1, g_b, h_b);   // res->g_b, h->h_b (xb dead)

  // t2 = gather27(h)@W32 -> f32 over AV (t dead)
  gg_kernel<27, 2><<<GG, B256, 0, stream>>>(h_b, WT32, nbr3b, nullptr, tf, nullptr);
  bnp_kernel<<<GBN, B256, 0, stream>>>(tf, psum, psq);
  bnfin_kernel<<<dim3(128), B256, 0, stream>>>(psum, psq, g2, b2, sc2, sh2);
  ew2_kernel<<<GEW, B256, 0, stream>>>(tf, g_b, sc2, sh2, yout);
}

// Round 6
// 469.631 us; speedup vs baseline: 1.0772x; 1.0682x over previous
//
#include <hip/hip_runtime.h>
#include <stdint.h>

// MinkFormerBlock on MI355X (gfx950). I/O: f32 in, f32 out (verified R8).
// R19: 64-row tiles, grid 512 -> 2 blocks/CU. Evidence: per-tap time is
// ~4000 cyc across ALL schedules tried (R13 drain 4224, R15 ring 3650,
// R18 decoupled-A conflict-free 4800) -> wave-level wait placement is not
// the limiter; the per-CU memory-pipe service time for the gather (128
// random 256B rows/tap/CU = 256-512 scattered lines, 16 discontiguous 64B
// segments per A-instr) is, and at 1 block/CU (grid 256, Occupancy 11.5%)
// it is SERIAL with the ~1030cyc MFMA floor. VGPR(132)/LDS(64KB) allow 2
// blocks/CU -- the limiter was grid size alone. Now: block = 64 rows x 128
// cols, 2 independent wave-groups/CU overlap one block's MFMA+ds_read with
// the other's gather-service/barriers. Per-block schedule = R18's proven
// structure (A per-wave in regs via plain loads -- compiler waitcnt pass
// protects spills; B via global_load_lds into 128B-stride measured-zero-
// conflict layout; one barrier/tap; own-B certified BEFORE barrier).
// Ledger/tap/wave: B 8 DMA, A 4, idx 1. Entering tap t: [A(t)4,idx(t+1)1].
// stageB->13 | GG_W(8) retires A+idx | loadA(4)+loadIdx(1)->13 |
// computeT | GG_WB(5) retires B(t+1) | barrier. Tail: (5),(4),(0).
//
//   cvt:       xb = bf16(x)            (aliases h_b, dead until ew1)
//   wt:        WT* = bf16(W^T)  [tap][Cout][Cin]
//   gg<1,0>:   a = xb @ Wa1 ; v = xb @ Wv1     (bf16)
//   gg<125,1>: g = gather(a,nbr5)@W5 * v       (bf16, fused gate)
//   gg<27,2>:  t = gather(g,nbr3a)@W31         (f32)
//   bn+fin -> sc1,sh1 ; ew1: res=bf16->g_b, h=bf16(relu)->h_b
//   gg<27,2>:  t2 = gather(h,nbr3b)@W32        (f32)
//   bn+fin -> sc2,sh2 ; ew2: d_out = relu(t2*sc+sh + res)  (f32)

#define NPTS 32768
#define C 128
#define EPS 1e-5f

typedef unsigned short u16;
using bfrag = __attribute__((ext_vector_type(8))) short;   // 8 bf16 = 4 VGPRs
using f32x4 = __attribute__((ext_vector_type(4))) float;

__device__ __forceinline__ float b2f(u16 u) {
  union { unsigned int i; float f; } x;
  x.i = ((unsigned int)u) << 16;
  return x.f;
}
__device__ __forceinline__ u16 f2b(float f) {
  union { float f; unsigned int i; } x;
  x.f = f;
  unsigned int r = x.i + 0x7FFFu + ((x.i >> 16) & 1u);   // RNE
  return (u16)(r >> 16);
}

// async global->LDS, 16 B per lane; LDS dest is wave-uniform base + lane*16.
__device__ __forceinline__ void g2l16(const void* g, void* l) {
  __builtin_amdgcn_global_load_lds(
      (const __attribute__((address_space(1))) unsigned int*)g,
      (__attribute__((address_space(3))) unsigned int*)l,
      16, 0, 0);
}

// counted vmcnt wait + scheduling fence
#define GG_W(N)                                                            \
  asm volatile("s_waitcnt vmcnt(" #N ")" ::: "memory");                    \
  __builtin_amdgcn_sched_barrier(0)

// counted vmcnt + lgkm drain, then block barrier (own-B certified BEFORE
// the barrier -> union certified after; lgkm drains ds_reads for WAR)
#define GG_WB(N)                                                           \
  asm volatile("s_waitcnt vmcnt(" #N ") lgkmcnt(0)" ::: "memory");         \
  __builtin_amdgcn_s_barrier();                                            \
  __builtin_amdgcn_sched_barrier(0)

// =====================================================================
// Gather-GEMM. Block = 64x128 output, 4 waves row-split: wave wv owns rows
// [wv*16,+16) x all 128 cols; acc 1x8 mfma_f32_16x16x32_bf16 fragments.
// A: per-wave register gather, double-buffered (af0/af1 = [4] bfrag),
//    plain global_load_dwordx4 (4/tap): lane (lsub,lm) reads 16B of row
//    id at byte kk*64+lsub*16.
// B: LDS 64KB = 2 x 32KB buffers, each [half][128 col][128 B] (half=K/2).
//    Stage: 8 x 1KB DMA/wave (4 col-groups x 2 halves); lane (r8,cs8):
//    global WT+col*256+h*128+((cs8^(col&7))<<4) -> LDS slot cs8 (slot s
//    holds global chunk s^(col&7)). Read (kk,lsub): half kk>>1, chunk
//    ((kk&1)*4+lsub)^(col&7) -- measured-zero-conflict (R15/R18).
// EPI: 0 bf16 out; 1 bf16(acc*vmul); 2 f32 out.
// =====================================================================
template <int NTAPS, int EPI>
__global__ __launch_bounds__(256, 1)
void gg_kernel(const u16* __restrict__ src, const u16* __restrict__ WT,
               const int* __restrict__ nbr, u16* __restrict__ outb,
               float* __restrict__ outf, const u16* __restrict__ vmul) {
  __shared__ uint4 lds[4096];          // 64 KB: two 32 KB B buffers
  char* const b0 = (char*)lds;
  char* const b1 = (char*)lds + 32768;

  const int tid  = threadIdx.x;
  const int lane = tid & 63;
  const int wv   = tid >> 6;
  const int lsub = lane >> 4, lm = lane & 15;
  const int r8   = lane >> 3;          // DMA: col within instr (0..7)
  const int cs8  = lane & 7;           // DMA: chunk slot (0..7, 16 B)
  const int row0 = blockIdx.x * 64;

  f32x4 acc[8];
#pragma unroll
  for (int j = 0; j < 8; j++) acc[j] = (f32x4)(0.0f);

  // ---- B stage: full tap into buffer nb, 8 DMA instrs/wave (4 col-groups
  // x 2 halves). 128B-stride layout: half h at nb + h*16384, col*128.
  auto stageB = [&](char* nb, int t) {
    const char* wt = (const char*)WT + ((size_t)t << 15);
#pragma unroll
    for (int j = 0; j < 4; j++) {
      const int col0 = wv * 32 + j * 8;
      const int col  = col0 + r8;
      const char* gp = wt + ((size_t)col << 8) + ((cs8 ^ (col & 7)) << 4);
      g2l16(gp,       nb + col0 * 128);            // half 0
      g2l16(gp + 128, nb + 16384 + col0 * 128);    // half 1
    }
  };

  // ---- idx load (plain: waitcnt pass protects all copies/spills)
  auto loadIdx = [&](int& d, int t) {
    const int gr = row0 + wv * 16 + lm;
    d = nbr[(size_t)gr * NTAPS + t];
  };

  // ---- A gather: 4 plain dwordx4 into register fragments (per-wave)
  auto loadA = [&](bfrag (&af)[4], int id) {
    const char* rb = (const char*)src + ((size_t)(unsigned)id << 8)
                   + lsub * 16;
#pragma unroll
    for (int kk = 0; kk < 4; kk++)
      af[kk] = *(const bfrag*)(rb + kk * 64);
  };

  // ---- one tap of MFMA: A from regs, B from LDS buffer buf
  auto computeT = [&](const bfrag (&af)[4], const char* buf) {
#pragma unroll
    for (int kk = 0; kk < 4; kk++) {
      const char* hb = buf + (kk >> 1) * 16384;
      bfrag bg[8];
#pragma unroll
      for (int ct = 0; ct < 8; ct++) {
        const int col = ct * 16 + lm;
        bg[ct] = *(const bfrag*)(hb + col * 128
                                 + ((((kk & 1) * 4 + lsub) ^ (col & 7)) << 4));
      }
#pragma unroll
      for (int ct = 0; ct < 8; ct++)
        acc[ct] = __builtin_amdgcn_mfma_f32_16x16x32_bf16(
            af[kk], bg[ct], acc[ct], 0, 0, 0);
    }
  };

  bfrag af0[4], af1[4];

  if constexpr (NTAPS == 1) {
    // dense 1x1: identity rows, single B stage, full drain before compute
#pragma unroll
    for (int kk = 0; kk < 4; kk++)
      af0[kk] = *(const bfrag*)((const char*)src
          + (size_t)(row0 + wv * 16 + lm) * 256 + kk * 64 + lsub * 16);
    stageB(b0, 0);
    GG_WB(0);
    computeT(af0, b0);
  } else {
    int idE, idO;                    // even-tap / odd-tap index
    // ---- prologue: idx(0),idx(1) -> A(0),B(0) -> full drain + barrier
    loadIdx(idE, 0);                 // 1 op
    loadIdx(idO, 1);                 // 1
    GG_W(1);                         // idx(0) ready
    loadA(af0, idE);                 // 4  A(0)
    stageB(b0, 0);                   // 8  B(0)
    GG_WB(0);                        // everything landed; entering tap 0: []

#pragma unroll 1
    for (int t = 0; t < NTAPS - 3; t += 2) {
      // ---- even tap t: compute af0 from b0
      stageB(b1, t + 1);             // -> [A(t)4, idx(t+1)1, B(t+1)8]
      GG_W(8);                       // retire A(t)+idx(t+1)  (t=0: no-op)
      loadA(af1, idO);               // A(t+1)
      loadIdx(idE, t + 2);
      __builtin_amdgcn_sched_barrier(0);
      computeT(af0, b0);
      GG_WB(5);                      // retire B(t+1); leave [A(t+1)4, idx1]
      // ---- odd tap t+1: compute af1 from b1
      stageB(b0, t + 2);
      GG_W(8);                       // retire A(t+1)+idx(t+2)
      loadA(af0, idE);               // A(t+2)
      loadIdx(idO, t + 3);
      __builtin_amdgcn_sched_barrier(0);
      computeT(af1, b1);
      GG_WB(5);                      // retire B(t+2)
    }
    // ---- tap NTAPS-3 (even)
    stageB(b1, NTAPS - 2);
    GG_W(8);
    loadA(af1, idO);                 // A(N-2)
    loadIdx(idE, NTAPS - 1);
    __builtin_amdgcn_sched_barrier(0);
    computeT(af0, b0);
    GG_WB(5);
    // ---- tap NTAPS-2 (odd): last B stage, last A load
    stageB(b0, NTAPS - 1);
    GG_W(8);                         // retire A(N-2)+idx(N-1)
    loadA(af0, idE);                 // A(N-1)
    __builtin_amdgcn_sched_barrier(0);
    computeT(af1, b1);
    GG_WB(4);                        // retire B(N-1); leave [A(N-1)4]
    // ---- tap NTAPS-1 (even)
    GG_W(0);                         // retire A(N-1)
    computeT(af0, b0);
  }

  // ---- epilogue write. C/D: col = lane&15, row = lsub*4 + reg.
  {
    const int rowb = row0 + wv * 16 + lsub * 4;
#pragma unroll
    for (int ct = 0; ct < 8; ct++) {
      const int c = ct * 16 + lm;
#pragma unroll
      for (int reg = 0; reg < 4; reg++) {
        const size_t off = (size_t)(rowb + reg) * C + c;
        const float v = acc[ct][reg];
        if (EPI == 0)      outb[off] = f2b(v);
        else if (EPI == 1) outb[off] = f2b(v * b2f(vmul[off]));
        else               outf[off] = v;
      }
    }
  }
}

// ---- f32 -> bf16 bulk convert (for x) ------------------------------------
__global__ __launch_bounds__(256)
void cvt_kernel(const float* __restrict__ x, u16* __restrict__ xb) {
  const int i = (blockIdx.x * 256 + threadIdx.x) * 4;
  const float4 v = *(const float4*)(x + i);
  ushort4 o;
  o.x = f2b(v.x); o.y = f2b(v.y); o.z = f2b(v.z); o.w = f2b(v.w);
  *(ushort4*)(xb + i) = o;
}

// ---- weights: f32 [..,Cin,Cout] -> bf16 [..,Cout,Cin] --------------------
__global__ __launch_bounds__(256)
void wt_kernel(const float* __restrict__ W5, const float* __restrict__ W31,
               const float* __restrict__ W32, const float* __restrict__ Wa1,
               const float* __restrict__ Wv1,
               u16* __restrict__ T5, u16* __restrict__ T31, u16* __restrict__ T32,
               u16* __restrict__ Ta1, u16* __restrict__ Tv1) {
  const int b = blockIdx.x;
  const float* w;
  u16* o;
  if (b < 125)       { w = W5  + (size_t)b * 16384;         o = T5  + (size_t)b * 16384; }
  else if (b < 152)  { w = W31 + (size_t)(b - 125) * 16384; o = T31 + (size_t)(b - 125) * 16384; }
  else if (b < 179)  { w = W32 + (size_t)(b - 152) * 16384; o = T32 + (size_t)(b - 152) * 16384; }
  else if (b == 179) { w = Wa1; o = Ta1; }
  else               { w = Wv1; o = Tv1; }
  __shared__ u16 tile[128 * 129];
  for (int i = threadIdx.x; i < C * C; i += 256)
    tile[(i & 127) * 129 + (i >> 7)] = f2b(w[i]);
  __syncthreads();
  for (int i = threadIdx.x; i < C * C; i += 256)
    o[i] = tile[(i >> 7) * 129 + (i & 127)];
}

// ---- BN partials (f32): block b owns rows [b*128, +128) ------------------
__global__ __launch_bounds__(256)
void bnp_kernel(const float* __restrict__ t, float* __restrict__ psum,
                float* __restrict__ psq) {
  const int b = blockIdx.x;
  const int c = threadIdx.x & 127;
  const int h = threadIdx.x >> 7;
  const float* p = t + (size_t)(b * 128 + h * 64) * C + c;
  float s = 0.f, q = 0.f;
#pragma unroll 8
  for (int j = 0; j < 64; j++) {
    const float v = p[(size_t)j * C];
    s += v; q += v * v;
  }
  __shared__ float ls[256], lq[256];
  ls[threadIdx.x] = s; lq[threadIdx.x] = q;
  __syncthreads();
  if (h == 0) {
    psum[b * 128 + c] = ls[c] + ls[c + 128];
    psq[b * 128 + c]  = lq[c] + lq[c + 128];
  }
}

// ---- bnfin: block c reduces 256 partials (parallel) ----------------------
__global__ __launch_bounds__(256)
void bnfin_kernel(const float* __restrict__ psum, const float* __restrict__ psq,
                  const float* __restrict__ gamma, const float* __restrict__ beta,
                  float* __restrict__ scale, float* __restrict__ shift) {
  const int c = blockIdx.x;
  const int t = threadIdx.x;
  float s = psum[(size_t)t * 128 + c];
  float q = psq[(size_t)t * 128 + c];
#pragma unroll
  for (int o = 32; o > 0; o >>= 1) {
    s += __shfl_down(s, o);
    q += __shfl_down(q, o);
  }
  __shared__ float ls[4], lq[4];
  if ((t & 63) == 0) { ls[t >> 6] = s; lq[t >> 6] = q; }
  __syncthreads();
  if (t == 0) {
    s = ls[0] + ls[1] + ls[2] + ls[3];
    q = lq[0] + lq[1] + lq[2] + lq[3];
    const float mean = s * (1.0f / NPTS);
    const float var  = q * (1.0f / NPTS) - mean * mean;
    const float sc   = rsqrtf(var + EPS) * gamma[c];
    scale[c] = sc;
    shift[c] = beta[c] - mean * sc;
  }
}

// ---- ew1: o = t*sc+sh + x; res=bf16(o); h=bf16(relu o) -------------------
__global__ __launch_bounds__(256)
void ew1_kernel(const float* __restrict__ t, const float* __restrict__ x,
                const float* __restrict__ scale, const float* __restrict__ shift,
                u16* __restrict__ res, u16* __restrict__ h) {
  const int i = blockIdx.x * 256 + threadIdx.x;
  const int c = i & 127;
  const float o = t[i] * scale[c] + shift[c] + x[i];
  res[i] = f2b(o);
  h[i] = f2b(o < 0.f ? 0.f : o);
}

// ---- ew2: y = relu(t2*sc+sh + res) -> f32 d_out --------------------------
__global__ __launch_bounds__(256)
void ew2_kernel(const float* __restrict__ t2, const u16* __restrict__ res,
                const float* __restrict__ scale, const float* __restrict__ shift,
                float* __restrict__ y) {
  const int i = blockIdx.x * 256 + threadIdx.x;
  const int c = i & 127;
  const float o = t2[i] * scale[c] + shift[c] + b2f(res[i]);
  y[i] = o < 0.f ? 0.f : o;
}

// =====================================================================
extern "C" void kernel_launch(void* const* d_in, const int* in_sizes, int n_in,
                              void* d_out, int out_size, void* d_ws, size_t ws_size,
                              hipStream_t stream) {
  (void)in_sizes; (void)n_in; (void)out_size; (void)ws_size;

  const float* x   = (const float*)d_in[0];
  const float* Wa1 = (const float*)d_in[1];
  const float* Wv1 = (const float*)d_in[2];
  const float* W5  = (const float*)d_in[3];
  const float* W31 = (const float*)d_in[4];
  const float* W32 = (const float*)d_in[5];
  const float* g1  = (const float*)d_in[6];
  const float* b1  = (const float*)d_in[7];
  const float* g2  = (const float*)d_in[8];
  const float* b2  = (const float*)d_in[9];
  const int* nbr5  = (const int*)d_in[10];
  const int* nbr3a = (const int*)d_in[11];
  const int* nbr3b = (const int*)d_in[12];

  // ---- workspace (~39.8 MB) ----
  char* w = (char*)d_ws;
  u16* WT5  = (u16*)w; w += 4096000;
  u16* WT31 = (u16*)w; w += 884736;
  u16* WT32 = (u16*)w; w += 884736;
  u16* WTa1 = (u16*)w; w += 32768;
  u16* WTv1 = (u16*)w; w += 32768;
  char* AV  = w;       w += 16777216;          // a | v ; later t/t2 (f32)
  u16*   a_b = (u16*)AV;
  u16*   v_b = (u16*)(AV + 8388608);
  float* tf  = (float*)AV;
  u16* g_b  = (u16*)w; w += 8388608;           // g ; later res (bf16)
  u16* h_b  = (u16*)w; w += 8388608;           // xb first, then h (bf16)
  u16* xb   = h_b;                             // alias: xb dead before ew1
  float* psum = (float*)w; w += 131072;
  float* psq  = (float*)w; w += 131072;
  float* sc1  = (float*)w; w += 512;
  float* sh1  = (float*)w; w += 512;
  float* sc2  = (float*)w; w += 512;
  float* sh2  = (float*)w; w += 512;

  const dim3 B256(256), GG(NPTS / 64), GBN(256), GEW(NPTS * C / 256);
  float* yout = (float*)d_out;

  cvt_kernel<<<dim3(NPTS * C / 1024), B256, 0, stream>>>(x, xb);
  wt_kernel<<<dim3(181), B256, 0, stream>>>(W5, W31, W32, Wa1, Wv1,
                                            WT5, WT31, WT32, WTa1, WTv1);

  // a = xb @ Wa1 ; v = xb @ Wv1
  gg_kernel<1, 0><<<GG, B256, 0, stream>>>(xb, WTa1, nullptr, a_b, nullptr, nullptr);
  gg_kernel<1, 0><<<GG, B256, 0, stream>>>(xb, WTv1, nullptr, v_b, nullptr, nullptr);

  // g = gather125(a)@W5 * v
  gg_kernel<125, 1><<<GG, B256, 0, stream>>>(a_b, WT5, nbr5, g_b, nullptr, v_b);

  // t = gather27(g)@W31 -> f32 over AV (a,v dead)
  gg_kernel<27, 2><<<GG, B256, 0, stream>>>(g_b, WT31, nbr3a, nullptr, tf, nullptr);
  bnp_kernel<<<GBN, B256, 0, stream>>>(tf, psum, psq);
  bnfin_kernel<<<dim3(128), B256, 0, stream>>>(psum, psq, g1, b1, sc1, sh1);
  ew1_kernel<<<GEW, B256, 0, stream>>>(tf, x, sc1, sh1, g_b, h_b);   // res->g_b, h->h_b (xb dead)

  // t2 = gather27(h)@W32 -> f32 over AV (t dead)
  gg_kernel<27, 2><<<GG, B256, 0, stream>>>(h_b, WT32, nbr3b, nullptr, tf, nullptr);
  bnp_kernel<<<GBN, B256, 0, stream>>>(tf, psum, psq);
  bnfin_kernel<<<dim3(128), B256, 0, stream>>>(psum, psq, g2, b2, sc2, sh2);
  ew2_kernel<<<GEW, B256, 0, stream>>>(tf, g_b, sc2, sh2, yout);
}